// Round 6
// baseline (207.222 us; speedup 1.0000x reference)
//
#include <hip/hip_runtime.h>

#define N_    8
#define C_    256
#define K_    7
#define HID_  10
#define OUTC_ 60
#define S_    16384
#define BN_EPS 1e-5f

// ---- workspace layout (float offsets, all 16B-aligned) ----
#define OFF_PP     0        // pool partials: [n][sh][oct][64] = 8*2*32*64 = 32768
#define OFF_DP     32768    // den partials:  [n*32+t][8] = 2048
#define OFF_EB     34816    // 64
#define OFF_M2     34880    // 3392
#define OFF_WPT80  38272    // N*256*80 = 163840
#define OFF_ATT    202112   // N*K*S = 917504
#define OFF_PART   1119616  // 512*120 = 61440
#define OFF_SCL    1181056  // 64
#define OFF_SHF    1181120  // 64
// total 1181184 floats ~= 4.7 MB

#define GLDS(g, l) __builtin_amdgcn_global_load_lds( \
    (const __attribute__((address_space(1))) unsigned int*)(g), \
    (__attribute__((address_space(3))) unsigned int*)(l), 16, 0, 0)

__device__ __forceinline__ float4 f4max(float4 a, float4 b) {
    return make_float4(fmaxf(a.x,b.x), fmaxf(a.y,b.y), fmaxf(a.z,b.z), fmaxf(a.w,b.w));
}

// ---------------- kernel A0: class softmax (once per pixel) + den partials ----
// 256 blocks xcd-chunked; 512 px/block, 2 px/thread (float2)
__global__ void __launch_bounds__(256) k_att(
        const float* __restrict__ seg, float* __restrict__ att,
        float* __restrict__ dp) {
    int b = blockIdx.x;
    int lin = (b & 7) * 32 + (b >> 3);
    int n = lin >> 5, t = lin & 31;
    int tid = threadIdx.x;
    const float* sp = seg + (size_t)n * K_ * S_ + t * 512 + tid * 2;
    float* ap = att + (size_t)n * K_ * S_ + t * 512 + tid * 2;

    float2 e[K_];
    float mx = -1e30f, my = -1e30f;
#pragma unroll
    for (int k = 0; k < K_; k++) {
        e[k] = *(const float2*)(sp + (size_t)k * S_);
        mx = fmaxf(mx, e[k].x); my = fmaxf(my, e[k].y);
    }
    float sx = 0.f, sy = 0.f;
#pragma unroll
    for (int k = 0; k < K_; k++) {
        e[k].x = __expf(e[k].x - mx); sx += e[k].x;
        e[k].y = __expf(e[k].y - my); sy += e[k].y;
    }
    float ix = 1.f / sx, iy = 1.f / sy;
    float dsum[K_];
#pragma unroll
    for (int k = 0; k < K_; k++) {
        float2 a = make_float2(e[k].x * ix, e[k].y * iy);
        *(float2*)(ap + (size_t)k * S_) = a;
        dsum[k] = a.x + a.y;
    }
    __shared__ float red[4][K_];
    int lane = tid & 63, wv = tid >> 6;
#pragma unroll
    for (int k = 0; k < K_; k++) {
        float v = dsum[k];
        for (int off = 32; off; off >>= 1) v += __shfl_xor(v, off, 64);
        if (lane == 0) red[wv][k] = v;
    }
    __syncthreads();
    if (tid < K_)
        dp[((size_t)n * 32 + t) * 8 + tid] =
            red[0][tid] + red[1][tid] + red[2][tid] + red[3][tid];
}

// ---------------- kernel A1: pooling GEMM (pure FMA, att from ws) ----------------
// 512 blocks xcd-chunked; per-block partials, no atomics
__global__ void __launch_bounds__(256) k_num(
        const float* __restrict__ fea, const float* __restrict__ att,
        float* __restrict__ pp) {
    int b = blockIdx.x;
    int lin = (b & 7) * 64 + (b >> 3);
    int n = lin >> 6, r = lin & 63;
    int oct = r >> 1, c0 = oct * 8, sh = r & 1;
    int tid = threadIdx.x;
    const float* ap = att + (size_t)n * K_ * S_ + sh * 8192 + tid * 4;
    const float* fp = fea + ((size_t)n * C_ + c0) * S_ + sh * 8192 + tid * 4;

    float acc[8][K_] = {};
#pragma unroll 2
    for (int it = 0; it < 8; it++) {
        int s = it * 1024;
        float4 av[K_], fv[8];
#pragma unroll
        for (int k = 0; k < K_; k++) av[k] = *(const float4*)(ap + (size_t)k * S_ + s);
#pragma unroll
        for (int c = 0; c < 8; c++) fv[c] = *(const float4*)(fp + (size_t)c * S_ + s);
#pragma unroll
        for (int c = 0; c < 8; c++)
#pragma unroll
            for (int k = 0; k < K_; k++)
                acc[c][k] += fv[c].x*av[k].x + fv[c].y*av[k].y
                           + fv[c].z*av[k].z + fv[c].w*av[k].w;
    }
    __shared__ float red[4][56];
    int lane = tid & 63, wv = tid >> 6;
#pragma unroll
    for (int i = 0; i < 56; i++) {
        float v = acc[i / K_][i % K_];
        for (int off = 32; off; off >>= 1) v += __shfl_xor(v, off, 64);
        if (lane == 0) red[wv][i] = v;
    }
    __syncthreads();
    if (tid < 56)
        pp[(((size_t)n * 2 + sh) * 32 + oct) * 64 + tid] =
            red[0][tid] + red[1][tid] + red[2][tid] + red[3][tid];
}

// ---------------- kernel B: reduce partials -> p_center -> wpt80, ebias, M2 ----
__global__ void k_center(const float* __restrict__ pp, const float* __restrict__ dp,
                         const float* __restrict__ Wq, const float* __restrict__ bq,
                         const float* __restrict__ Wk, const float* __restrict__ bk,
                         const float* __restrict__ Wp,
                         float* __restrict__ eb, float* __restrict__ m2,
                         float* __restrict__ wpt80) {
    int n = blockIdx.x, tid = threadIdx.x;
    __shared__ float pc[C_ * K_];     // [c][k]
    __shared__ float ql[HID_ * K_];   // [o][k]
    __shared__ float dinv[K_];
    if (tid < K_) {
        float d = 0.f;
        for (int t = 0; t < 32; t++) d += dp[((size_t)n * 32 + t) * 8 + tid];
        dinv[tid] = 1.f / d;
    }
    __syncthreads();
    for (int i = tid; i < C_ * K_; i += 256) {
        int c = i / K_, k = i - c * K_;
        int oct = c >> 3, ci = c & 7;
        float v = pp[(((size_t)n * 2 + 0) * 32 + oct) * 64 + ci * K_ + k]
                + pp[(((size_t)n * 2 + 1) * 32 + oct) * 64 + ci * K_ + k];
        pc[i] = v * dinv[k];
    }
    __syncthreads();
    if (tid < HID_ * K_) {
        int o = tid / K_, k = tid % K_;
        float s = bq[o];
        for (int c = 0; c < C_; c++) s += Wq[o * C_ + c] * pc[c * K_ + k];
        ql[tid] = s;
    }
    __syncthreads();
    // wpt80[c][80]: col 20w+j (j<17) = output o=17w+j; o<60 -> Wp1^T, 60..66 -> Wqk
    for (int i = tid; i < C_ * 80; i += 256) {
        int c = i / 80, cc = i % 80;
        int w = cc / 20, j = cc % 20;
        float v = 0.f;
        if (j < 17) {
            int o = 17 * w + j;
            if (o < 60) v = Wp[o * 2 * C_ + c];
            else if (o < 67) {
                int k = o - 60;
                for (int o2 = 0; o2 < HID_; o2++) v += ql[o2 * K_ + k] * Wk[o2 * C_ + c];
            }
        }
        wpt80[(size_t)n * C_ * 80 + i] = v;
    }
    if (tid < K_) {
        float s = 0.f;
        for (int o = 0; o < HID_; o++) s += ql[o * K_ + tid] * bk[o];
        eb[n * K_ + tid] = s;
    }
    for (int i = tid; i < OUTC_ * K_; i += 256) {
        int o = i / K_, k = i % K_;
        float s = 0.f;
        for (int c = 0; c < C_; c++) s += Wp[o * 2 * C_ + C_ + c] * pc[c * K_ + k];
        m2[(size_t)n * OUTC_ * K_ + i] = s;
    }
}

// ---------------- kernel C: fused energy/softmax/projection ----------------
// 512 blocks xcd-chunked; wave w owns outputs 17w..17w+16; thread owns 4 px
__global__ void __launch_bounds__(256, 2) k_main(
        const float* __restrict__ fea, const float* __restrict__ wpt80,
        const float* __restrict__ ebias, const float* __restrict__ m2,
        float* __restrict__ y, float* __restrict__ part) {
    int g = blockIdx.x;
    int lin = (g & 7) * 64 + (g >> 3);
    int n = lin >> 6, tile = lin & 63;
    int tid = threadIdx.x, lane = tid & 63, wv = tid >> 6;

    __shared__ __align__(16) float sw[2][5120];      // 2 x 20KB weight chunks
    __shared__ __align__(16) float sm2[424];
    __shared__ __align__(16) float a_lds[K_][256];
    __shared__ float tot[120];

    for (int i = tid; i < OUTC_ * K_; i += 256)
        sm2[i] = m2[(size_t)n * OUTC_ * K_ + i];

    const float* wsrc = wpt80 + (size_t)n * (C_ * 80);
    const float* fp = fea + (size_t)n * C_ * S_ + tile * 256 + lane * 4;

    float4 acc[17];
#pragma unroll
    for (int i = 0; i < 17; i++) acc[i] = make_float4(0.f, 0.f, 0.f, 0.f);

    {   // stage chunk 0
#pragma unroll
        for (int i = 0; i < 5; i++) {
            int fi = i * 1024 + wv * 256;            // wave-uniform lds base
            GLDS(wsrc + fi + lane * 4, &sw[0][fi]);
        }
    }
    // 8-deep fea channel prefetch (issued AFTER the GLDS -> counted waits work)
    float4 fbuf[8];
#pragma unroll
    for (int j = 0; j < 8; j++) fbuf[j] = *(const float4*)(fp + (size_t)j * S_);

    // GLDS are the 5 oldest outstanding; allow the 8 newest (fbuf) to stay in flight
    asm volatile("s_waitcnt vmcnt(8) lgkmcnt(0)" ::: "memory");
    __builtin_amdgcn_s_barrier();

    const int wb = 20 * wv;
    for (int ch = 0; ch < 4; ch++) {
        int bb = ch & 1;
        if (ch < 3) {
            const float* s1 = wsrc + (ch + 1) * 5120;
#pragma unroll
            for (int i = 0; i < 5; i++) {
                int fi = i * 1024 + wv * 256;
                GLDS(s1 + fi + lane * 4, &sw[bb ^ 1][fi]);
            }
        }
#pragma unroll 8
        for (int cc = 0; cc < 64; cc++) {
            int cg = ch * 64 + cc;
            float4 f = fbuf[cg & 7];
            fbuf[cg & 7] = *(const float4*)(fp + (size_t)((cg + 8) & 255) * S_);
            const float* wr = &sw[bb][cc * 80 + wb];         // wave-uniform -> broadcast
            float4 w0 = *(const float4*)wr;
            float4 w1 = *(const float4*)(wr + 4);
            float4 w2 = *(const float4*)(wr + 8);
            float4 w3 = *(const float4*)(wr + 12);
            float wx = wr[16];
#define FMA4(j, ww) acc[j].x += (ww) * f.x; acc[j].y += (ww) * f.y; \
                    acc[j].z += (ww) * f.z; acc[j].w += (ww) * f.w;
            FMA4(0, w0.x) FMA4(1, w0.y) FMA4(2, w0.z) FMA4(3, w0.w)
            FMA4(4, w1.x) FMA4(5, w1.y) FMA4(6, w1.z) FMA4(7, w1.w)
            FMA4(8, w2.x) FMA4(9, w2.y) FMA4(10, w2.z) FMA4(11, w2.w)
            FMA4(12, w3.x) FMA4(13, w3.y) FMA4(14, w3.z) FMA4(15, w3.w)
            FMA4(16, wx)
#undef FMA4
        }
        // counted wait: next chunk's 5 GLDS (issued 64 loads ago) are done;
        // keep the 8 newest fea prefetches in flight across the barrier
        asm volatile("s_waitcnt vmcnt(8)" ::: "memory");
        __builtin_amdgcn_s_barrier();
    }

    // wave 3 holds energies (outputs 60..66 = acc[9..15]); softmax over k per px
    if (wv == 3) {
        float4 a[K_];
#pragma unroll
        for (int k = 0; k < K_; k++) {
            float e = ebias[n * K_ + k];
            a[k] = make_float4(acc[9+k].x + e, acc[9+k].y + e,
                               acc[9+k].z + e, acc[9+k].w + e);
        }
        float4 mm = a[0];
#pragma unroll
        for (int k = 1; k < K_; k++) mm = f4max(mm, a[k]);
        float4 sum = make_float4(0.f, 0.f, 0.f, 0.f);
#pragma unroll
        for (int k = 0; k < K_; k++) {
            a[k] = make_float4(__expf(a[k].x - mm.x), __expf(a[k].y - mm.y),
                               __expf(a[k].z - mm.z), __expf(a[k].w - mm.w));
            sum.x += a[k].x; sum.y += a[k].y; sum.z += a[k].z; sum.w += a[k].w;
        }
        float4 inv = make_float4(1.f/sum.x, 1.f/sum.y, 1.f/sum.z, 1.f/sum.w);
#pragma unroll
        for (int k = 0; k < K_; k++)
            ((float4*)&a_lds[k][0])[lane] =
                make_float4(a[k].x*inv.x, a[k].y*inv.y, a[k].z*inv.z, a[k].w*inv.w);
    }
    __syncthreads();

    float4 a4[K_];
#pragma unroll
    for (int k = 0; k < K_; k++) a4[k] = ((const float4*)&a_lds[k][0])[lane];
    int nout = (wv == 3) ? 9 : 17;
    int ob = wv * 17;
#pragma unroll
    for (int i = 0; i < 17; i++) {
        if (i < nout) {
            int o = ob + i;
            float4 s = make_float4(0.f, 0.f, 0.f, 0.f);
#pragma unroll
            for (int k = 0; k < K_; k++) {
                float mv = sm2[o * K_ + k];
                s.x += mv * a4[k].x; s.y += mv * a4[k].y;
                s.z += mv * a4[k].z; s.w += mv * a4[k].w;
            }
            acc[i].x += s.x; acc[i].y += s.y; acc[i].z += s.z; acc[i].w += s.w;
        }
    }

    // store pre-BN y + per-block BN partials
    float* yp = y + (size_t)n * OUTC_ * S_ + tile * 256 + lane * 4;
#pragma unroll
    for (int i = 0; i < 17; i++) {
        if (i < nout) {
            int o = ob + i;
            *(float4*)(yp + (size_t)o * S_) = acc[i];
            float sm = acc[i].x + acc[i].y + acc[i].z + acc[i].w;
            float sq = acc[i].x*acc[i].x + acc[i].y*acc[i].y +
                       acc[i].z*acc[i].z + acc[i].w*acc[i].w;
            for (int off = 32; off; off >>= 1) {
                sm += __shfl_xor(sm, off, 64);
                sq += __shfl_xor(sq, off, 64);
            }
            if (lane == 0) { tot[o] = sm; tot[60 + o] = sq; }
        }
    }
    __syncthreads();
    if (tid < 120) part[(size_t)blockIdx.x * 120 + tid] = tot[tid];
}

// ---------------- kernel D: BN statistics ----------------
__global__ void k_bn(const float* __restrict__ part, const float* __restrict__ gamma,
                     const float* __restrict__ beta, float* __restrict__ scl,
                     float* __restrict__ shf) {
    int t = threadIdx.x & 127, q = threadIdx.x >> 7;   // 512 threads
    __shared__ float red[4][120];
    __shared__ float tot[120];
    if (t < 120) {
        float s = 0.f;
        for (int b = q * 128; b < q * 128 + 128; b++) s += part[(size_t)b * 120 + t];
        red[q][t] = s;
    }
    __syncthreads();
    if (threadIdx.x < 120)
        tot[threadIdx.x] = red[0][threadIdx.x] + red[1][threadIdx.x] +
                           red[2][threadIdx.x] + red[3][threadIdx.x];
    __syncthreads();
    if (threadIdx.x < OUTC_) {
        const float invn = 1.f / (float)(N_ * S_);
        float mean = tot[threadIdx.x] * invn;
        float var = tot[60 + threadIdx.x] * invn - mean * mean;
        float sc = gamma[threadIdx.x] * rsqrtf(var + BN_EPS);
        scl[threadIdx.x] = sc;
        shf[threadIdx.x] = beta[threadIdx.x] - mean * sc;
    }
}

// ---------------- kernel E: in-place BN apply + ReLU ----------------
__global__ void k_apply(float* __restrict__ y, const float* __restrict__ scl,
                        const float* __restrict__ shf) {
    int idx = blockIdx.x * 256 + threadIdx.x;          // float4 index
    int o = (idx >> 12) % OUTC_;
    float4 v = ((const float4*)y)[idx];
    float a = scl[o], b = shf[o];
    v.x = fmaxf(v.x * a + b, 0.f);
    v.y = fmaxf(v.y * a + b, 0.f);
    v.z = fmaxf(v.z * a + b, 0.f);
    v.w = fmaxf(v.w * a + b, 0.f);
    ((float4*)y)[idx] = v;
}

extern "C" void kernel_launch(void* const* d_in, const int* in_sizes, int n_in,
                              void* d_out, int out_size, void* d_ws, size_t ws_size,
                              hipStream_t stream) {
    const float* p_fea = (const float*)d_in[0];
    const float* p_seg = (const float*)d_in[1];
    const float* Wq    = (const float*)d_in[2];
    const float* bq    = (const float*)d_in[3];
    const float* Wk    = (const float*)d_in[4];
    const float* bk    = (const float*)d_in[5];
    const float* Wp    = (const float*)d_in[6];
    const float* gamma = (const float*)d_in[7];
    const float* beta  = (const float*)d_in[8];

    float* ws    = (float*)d_ws;
    float* pp    = ws + OFF_PP;
    float* dp    = ws + OFF_DP;
    float* eb    = ws + OFF_EB;
    float* m2    = ws + OFF_M2;
    float* wpt80 = ws + OFF_WPT80;
    float* att   = ws + OFF_ATT;
    float* part  = ws + OFF_PART;
    float* scl   = ws + OFF_SCL;
    float* shf   = ws + OFF_SHF;
    float* ybuf  = (float*)d_out;

    k_att<<<256, 256, 0, stream>>>(p_seg, att, dp);
    k_num<<<512, 256, 0, stream>>>(p_fea, att, pp);
    k_center<<<8, 256, 0, stream>>>(pp, dp, Wq, bq, Wk, bk, Wp, eb, m2, wpt80);
    k_main<<<512, 256, 0, stream>>>(p_fea, wpt80, eb, m2, ybuf, part);
    k_bn<<<1, 512, 0, stream>>>(part, gamma, beta, scl, shf);
    k_apply<<<(N_ * OUTC_ * S_ / 4) / 256, 256, 0, stream>>>(ybuf, scl, shf);
}